// Round 4
// baseline (162.776 us; speedup 1.0000x reference)
//
#include <hip/hip_runtime.h>
#include <math.h>

#define BB 8
#define LL 2048
#define HH 1024
#define JL 64
#define TT 1984          // LL - JL
#define NT 31            // k1 tiles per batch (TT/64)
#define PAD 68           // 272B row stride: 16B-aligned; rows 4 apart differ by 16 banks

// workspace layout (float offsets)
#define S_OFF    0
#define S_SZ     (BB*TT*JL)
#define QT_OFF   (S_OFF + S_SZ)
#define QT_SZ    (BB*JL)
#define PQ_OFF   (QT_OFF + QT_SZ)
#define PQ_SZ    (BB*NT*HH)
#define PDEN_OFF (PQ_OFF + PQ_SZ)
#define PMAX_OFF (PDEN_OFF + 256)
#define Q2C_OFF  (PMAX_OFF + 256)

// ---- k0: copy query to out, compute q_term[b,j] = <query[b,j,:], w_q> ----
__global__ __launch_bounds__(256) void k0(const float* __restrict__ enc,
                                          const float* __restrict__ w,
                                          float* __restrict__ out,
                                          float* __restrict__ ws) {
  int j = blockIdx.x, b = blockIdx.y, tid = threadIdx.x;
  const float* qrow = enc + ((size_t)b*LL + j)*HH;
  float4 v = *(const float4*)(qrow + tid*4);
  *(float4*)(out + ((size_t)b*JL + j)*HH + tid*4) = v;
  float4 wq = *(const float4*)(w + HH + tid*4);
  float a = v.x*wq.x + v.y*wq.y + v.z*wq.z + v.w*wq.w;
  #pragma unroll
  for (int o = 32; o > 0; o >>= 1) a += __shfl_xor(a, o);
  __shared__ float red[4];
  if ((tid & 63) == 0) red[tid >> 6] = a;
  __syncthreads();
  if (tid == 0) ws[QT_OFF + b*JL + j] = red[0]+red[1]+red[2]+red[3];
}

// ---- k1: S GEMM + row max + FUSED partial softmax-weighted q2c (flash-style) ----
// 512 threads, 64x64 output tile, register double-buffered staging.
__global__ __launch_bounds__(512) void k1(const float* __restrict__ enc,
                                          const float* __restrict__ w,
                                          float* __restrict__ ws) {
  __shared__ float ctx_s[64][PAD];     // [t_local][k]
  __shared__ float qm_t[64][PAD];      // [k][j], col XOR-swizzled
  __shared__ float m_s[64];            // per-row max of S
  __shared__ float w_s[64];            // exp(m - M_blk)
  __shared__ float q2c_half[256][4];   // cross-half reduce
  const int b = blockIdx.y, bx = blockIdx.x;
  const int t0 = bx * 64;
  const int tid = threadIdx.x;
  const int tr = tid >> 4, tc = tid & 15;   // tr 0..31, rows {2tr,2tr+1}
  const float* ctx = enc + ((size_t)b*LL + JL)*HH;
  const float* qry = enc + (size_t)b*LL*HH;
  const float* wc = w;
  const float* wm = w + 2*HH;
  float4 acc0 = {0,0,0,0}, acc1 = {0,0,0,0};
  float4 cv[2], q4[2], m4[2], w4[2];
  // initial stage load (h0 = 0)
  #pragma unroll
  for (int it = 0; it < 2; ++it) {
    int idx = it*512 + tid;
    int r = idx >> 4, c4 = idx & 15;
    cv[it] = *(const float4*)(ctx + (size_t)(t0 + r)*HH + c4*4);
    q4[it] = *(const float4*)(qry + (size_t)r*HH + c4*4);
    m4[it] = *(const float4*)(wm + c4*4);
    w4[it] = *(const float4*)(wc + c4*4);
  }
  for (int h0 = 0; h0 < HH; h0 += 64) {
    #pragma unroll
    for (int it = 0; it < 2; ++it) {
      int idx = it*512 + tid;
      int r = idx >> 4, c4 = idx & 15;
      *(float4*)&ctx_s[r][c4*4] = cv[it];
      int col = r ^ (c4*4);             // involution swizzle
      qm_t[c4*4 + 0][col] = q4[it].x*m4[it].x + w4[it].x;
      qm_t[c4*4 + 1][col] = q4[it].y*m4[it].y + w4[it].y;
      qm_t[c4*4 + 2][col] = q4[it].z*m4[it].z + w4[it].z;
      qm_t[c4*4 + 3][col] = q4[it].w*m4[it].w + w4[it].w;
    }
    __syncthreads();
    if (h0 + 64 < HH) {                 // prefetch next chunk into regs
      int h1 = h0 + 64;
      #pragma unroll
      for (int it = 0; it < 2; ++it) {
        int idx = it*512 + tid;
        int r = idx >> 4, c4 = idx & 15;
        cv[it] = *(const float4*)(ctx + (size_t)(t0 + r)*HH + h1 + c4*4);
        q4[it] = *(const float4*)(qry + (size_t)r*HH + h1 + c4*4);
        m4[it] = *(const float4*)(wm + h1 + c4*4);
        w4[it] = *(const float4*)(wc + h1 + c4*4);
      }
    }
    #pragma unroll 4
    for (int k4 = 0; k4 < 16; ++k4) {
      float4 a0 = *(const float4*)&ctx_s[tr*2 + 0][k4*4];
      float4 a1 = *(const float4*)&ctx_s[tr*2 + 1][k4*4];
      const int colb = 4*(tc ^ k4);
      float4 b0 = *(const float4*)&qm_t[k4*4 + 0][colb];
      float4 b1 = *(const float4*)&qm_t[k4*4 + 1][colb];
      float4 b2 = *(const float4*)&qm_t[k4*4 + 2][colb];
      float4 b3 = *(const float4*)&qm_t[k4*4 + 3][colb];
      acc0.x += a0.x*b0.x + a0.y*b1.x + a0.z*b2.x + a0.w*b3.x;
      acc0.y += a0.x*b0.y + a0.y*b1.y + a0.z*b2.y + a0.w*b3.y;
      acc0.z += a0.x*b0.z + a0.y*b1.z + a0.z*b2.z + a0.w*b3.z;
      acc0.w += a0.x*b0.w + a0.y*b1.w + a0.z*b2.w + a0.w*b3.w;
      acc1.x += a1.x*b0.x + a1.y*b1.x + a1.z*b2.x + a1.w*b3.x;
      acc1.y += a1.x*b0.y + a1.y*b1.y + a1.z*b2.y + a1.w*b3.y;
      acc1.z += a1.x*b0.z + a1.y*b1.z + a1.z*b2.z + a1.w*b3.z;
      acc1.w += a1.x*b0.w + a1.y*b1.w + a1.z*b2.w + a1.w*b3.w;
    }
    __syncthreads();
  }
  // epilogue: S write + row max
  float4 qt4 = *(const float4*)(ws + QT_OFF + (size_t)b*JL + tc*4);
  float* Sp = ws + S_OFF + ((size_t)b*TT + t0)*JL;
  {
    float4 s;
    s.x = acc0.x + qt4.x; s.y = acc0.y + qt4.y; s.z = acc0.z + qt4.z; s.w = acc0.w + qt4.w;
    *(float4*)(Sp + (size_t)(tr*2 + 0)*JL + tc*4) = s;
    float rm = fmaxf(fmaxf(s.x,s.y), fmaxf(s.z,s.w));
    #pragma unroll
    for (int o = 1; o < 16; o <<= 1) rm = fmaxf(rm, __shfl_xor(rm, o));
    if (tc == 0) m_s[tr*2 + 0] = rm;
    s.x = acc1.x + qt4.x; s.y = acc1.y + qt4.y; s.z = acc1.z + qt4.z; s.w = acc1.w + qt4.w;
    *(float4*)(Sp + (size_t)(tr*2 + 1)*JL + tc*4) = s;
    rm = fmaxf(fmaxf(s.x,s.y), fmaxf(s.z,s.w));
    #pragma unroll
    for (int o = 1; o < 16; o <<= 1) rm = fmaxf(rm, __shfl_xor(rm, o));
    if (tc == 0) m_s[tr*2 + 1] = rm;
  }
  __syncthreads();
  // wave 0: block max, weights, partial denominator
  if (tid < 64) {
    float mv = m_s[tid];
    float M = mv;
    #pragma unroll
    for (int o = 1; o < 64; o <<= 1) M = fmaxf(M, __shfl_xor(M, o));
    float wv = __expf(mv - M);
    w_s[tid] = wv;
    float den = wv;
    #pragma unroll
    for (int o = 1; o < 64; o <<= 1) den += __shfl_xor(den, o);
    if (tid == 0) {
      ws[PDEN_OFF + b*NT + bx] = den;
      ws[PMAX_OFF + b*NT + bx] = M;
    }
  }
  __syncthreads();
  // partial q2c: sum_t w_s[t] * ctx[t0+t, :]  (ctx tile is L2-hot)
  {
    const int half = tid >> 8;            // 0 or 1
    const int hc = (tid & 255) * 4;
    const float* ctxb = ctx + (size_t)t0*HH + hc;
    float4 a = {0,0,0,0};
    const int tb = half*32;
    #pragma unroll 8
    for (int t = 0; t < 32; ++t) {
      float wv = w_s[tb + t];
      float4 vv = *(const float4*)(ctxb + (size_t)(tb + t)*HH);
      a.x += wv*vv.x; a.y += wv*vv.y; a.z += wv*vv.z; a.w += wv*vv.w;
    }
    if (half == 1) *(float4*)&q2c_half[tid & 255][0] = a;
    __syncthreads();
    if (half == 0) {
      float4 o4 = *(float4*)&q2c_half[tid][0];
      a.x += o4.x; a.y += o4.y; a.z += o4.z; a.w += o4.w;
      *(float4*)(ws + PQ_OFF + ((size_t)(b*NT + bx))*HH + hc) = a;
    }
  }
}

// ---- k2: combine partials with flash rescale -> q2c[b,h] ----
__global__ __launch_bounds__(256) void k2(float* __restrict__ ws) {
  int b = blockIdx.x, tid = threadIdx.x;
  float M = -1e30f;
  #pragma unroll
  for (int c = 0; c < NT; ++c) M = fmaxf(M, ws[PMAX_OFF + b*NT + c]);
  float den = 0.f;
  #pragma unroll
  for (int c = 0; c < NT; ++c)
    den += __expf(ws[PMAX_OFF + b*NT + c] - M) * ws[PDEN_OFF + b*NT + c];
  float inv = 1.f / den;
  float4 a = {0,0,0,0};
  for (int c = 0; c < NT; ++c) {
    float e = __expf(ws[PMAX_OFF + b*NT + c] - M);
    float4 v = *(const float4*)(ws + PQ_OFF + ((size_t)(b*NT + c))*HH + tid*4);
    a.x += e*v.x; a.y += e*v.y; a.z += e*v.z; a.w += e*v.w;
  }
  a.x *= inv; a.y *= inv; a.z *= inv; a.w *= inv;
  *(float4*)(ws + Q2C_OFF + (size_t)b*HH + tid*4) = a;
}

// ---- k4: softmax_j(S) -> c2q -> G assembly; slab-0 copy issued early ----
__global__ __launch_bounds__(256) void k4(const float* __restrict__ enc,
                                          const float* __restrict__ ws,
                                          float* __restrict__ out) {
  __shared__ float4 P4[16][16];
  const int b = blockIdx.y, t0 = blockIdx.x*16, tid = threadIdx.x;
  const int r = tid >> 4, sub = tid & 15;
  const float* Sp = ws + S_OFF + ((size_t)b*TT + t0)*JL;
  float4 v = *(const float4*)(Sp + (size_t)r*JL + sub*4);   // issue S load first
  const float* ctx = enc + ((size_t)b*LL + JL + t0)*HH;
  float* G = out + (size_t)BB*JL*HH + ((size_t)b*TT + t0)*4096;
  // slab 0 (pure ctx copy) — overlaps with everything below
  #pragma unroll
  for (int rr = 0; rr < 16; ++rr) {
    float4 cv = *(const float4*)(ctx + (size_t)rr*HH + tid*4);
    *(float4*)(G + (size_t)rr*4096 + tid*4) = cv;
  }
  float mx = fmaxf(fmaxf(v.x,v.y), fmaxf(v.z,v.w));
  #pragma unroll
  for (int o = 1; o < 16; o <<= 1) mx = fmaxf(mx, __shfl_xor(mx, o));
  float e0 = __expf(v.x-mx), e1 = __expf(v.y-mx), e2 = __expf(v.z-mx), e3 = __expf(v.w-mx);
  float s = e0+e1+e2+e3;
  #pragma unroll
  for (int o = 1; o < 16; o <<= 1) s += __shfl_xor(s, o);
  float inv = 1.f/s;
  P4[r][sub] = make_float4(e0*inv, e1*inv, e2*inv, e3*inv);
  __syncthreads();
  const float* qry = enc + (size_t)b*LL*HH;
  float4 acc[16];
  #pragma unroll
  for (int i = 0; i < 16; ++i) acc[i] = make_float4(0,0,0,0);
  for (int jc = 0; jc < 16; ++jc) {
    float4 q0 = *(const float4*)(qry + (size_t)(jc*4+0)*HH + tid*4);
    float4 q1 = *(const float4*)(qry + (size_t)(jc*4+1)*HH + tid*4);
    float4 q2v = *(const float4*)(qry + (size_t)(jc*4+2)*HH + tid*4);
    float4 q3 = *(const float4*)(qry + (size_t)(jc*4+3)*HH + tid*4);
    #pragma unroll
    for (int rr = 0; rr < 16; ++rr) {
      float4 p = P4[rr][jc];
      acc[rr].x += p.x*q0.x + p.y*q1.x + p.z*q2v.x + p.w*q3.x;
      acc[rr].y += p.x*q0.y + p.y*q1.y + p.z*q2v.y + p.w*q3.y;
      acc[rr].z += p.x*q0.z + p.y*q1.z + p.z*q2v.z + p.w*q3.z;
      acc[rr].w += p.x*q0.w + p.y*q1.w + p.z*q2v.w + p.w*q3.w;
    }
  }
  float4 qc = *(const float4*)(ws + Q2C_OFF + (size_t)b*HH + tid*4);
  #pragma unroll
  for (int rr = 0; rr < 16; ++rr) {
    float4 cv = *(const float4*)(ctx + (size_t)rr*HH + tid*4);  // L1/L2 hit
    float4 c2 = acc[rr];
    float* Gr = G + (size_t)rr*4096;
    *(float4*)(Gr + 1024 + tid*4) = c2;
    *(float4*)(Gr + 2048 + tid*4) = make_float4(cv.x*c2.x, cv.y*c2.y, cv.z*c2.z, cv.w*c2.w);
    *(float4*)(Gr + 3072 + tid*4) = make_float4(cv.x*qc.x, cv.y*qc.y, cv.z*qc.z, cv.w*qc.w);
  }
}

extern "C" void kernel_launch(void* const* d_in, const int* in_sizes, int n_in,
                              void* d_out, int out_size, void* d_ws, size_t ws_size,
                              hipStream_t stream) {
  const float* enc = (const float*)d_in[0];
  const float* w   = (const float*)d_in[1];
  float* out = (float*)d_out;
  float* ws  = (float*)d_ws;
  k0<<<dim3(JL, BB), 256, 0, stream>>>(enc, w, out, ws);
  k1<<<dim3(NT, BB), 512, 0, stream>>>(enc, w, ws);
  k2<<<BB, 256, 0, stream>>>(ws);
  k4<<<dim3(TT/16, BB), 256, 0, stream>>>(enc, ws, out);
}

// Round 5
// 144.328 us; speedup vs baseline: 1.1278x; 1.1278x over previous
//
#include <hip/hip_runtime.h>
#include <math.h>

#define BB 8
#define LL 2048
#define HH 1024
#define JL 64
#define TT 1984          // LL - JL
#define NT 31            // k1 tiles per batch (TT/64)
#define PAD 68           // 272B row stride: 16B-aligned; rows 4 apart differ by 16 banks

// workspace layout (float offsets)
#define S_OFF    0
#define S_SZ     (BB*TT*JL)
#define QT_OFF   (S_OFF + S_SZ)
#define QT_SZ    (BB*JL)
#define PQ_OFF   (QT_OFF + QT_SZ)
#define PQ_SZ    (BB*NT*HH)
#define PDEN_OFF (PQ_OFF + PQ_SZ)
#define PMAX_OFF (PDEN_OFF + 256)
#define Q2C_OFF  (PMAX_OFF + 256)

// ---- k0: copy query to out, compute q_term[b,j] = <query[b,j,:], w_q> ----
__global__ __launch_bounds__(256) void k0(const float* __restrict__ enc,
                                          const float* __restrict__ w,
                                          float* __restrict__ out,
                                          float* __restrict__ ws) {
  int j = blockIdx.x, b = blockIdx.y, tid = threadIdx.x;
  const float* qrow = enc + ((size_t)b*LL + j)*HH;
  float4 v = *(const float4*)(qrow + tid*4);
  *(float4*)(out + ((size_t)b*JL + j)*HH + tid*4) = v;
  float4 wq = *(const float4*)(w + HH + tid*4);
  float a = v.x*wq.x + v.y*wq.y + v.z*wq.z + v.w*wq.w;
  #pragma unroll
  for (int o = 32; o > 0; o >>= 1) a += __shfl_xor(a, o);
  __shared__ float red[4];
  if ((tid & 63) == 0) red[tid >> 6] = a;
  __syncthreads();
  if (tid == 0) ws[QT_OFF + b*JL + j] = red[0]+red[1]+red[2]+red[3];
}

// ---- k1: S GEMM (round-3 proven core) + flash partial-q2c epilogue ----
// S = sum_h ctx[t,h]*(w_m[h]*q[j,h] + w_c[h]) + q_term[j]
__global__ __launch_bounds__(256) void k1(const float* __restrict__ enc,
                                          const float* __restrict__ w,
                                          float* __restrict__ ws) {
  __shared__ float ctx_s[64][PAD];   // [t_local][k]
  __shared__ float qm_t[64][PAD];    // [k][j], col XOR-swizzled
  __shared__ float m_s[64];          // per-row max of S
  __shared__ float w_s[64];          // exp(m - M_blk)
  const int b = blockIdx.y, bx = blockIdx.x;
  const int t0 = bx * 64;
  const int tid = threadIdx.x;
  const int tr = tid >> 4, tc = tid & 15;
  const float* ctx = enc + ((size_t)b*LL + JL)*HH;
  const float* qry = enc + (size_t)b*LL*HH;
  const float* wc = w;
  const float* wm = w + 2*HH;
  float acc[4][4] = {};
  for (int h0 = 0; h0 < HH; h0 += 64) {
    #pragma unroll
    for (int it = 0; it < 4; ++it) {
      int idx = it*256 + tid;
      int r = idx >> 4, c4 = idx & 15;
      float4 cv = *(const float4*)(ctx + (size_t)(t0 + r)*HH + h0 + c4*4);
      *(float4*)&ctx_s[r][c4*4] = cv;
      float4 q4 = *(const float4*)(qry + (size_t)r*HH + h0 + c4*4);
      float4 m4 = *(const float4*)(wm + h0 + c4*4);
      float4 w4 = *(const float4*)(wc + h0 + c4*4);
      int col = r ^ (c4*4);           // swizzle: involution per k-group
      qm_t[c4*4 + 0][col] = q4.x*m4.x + w4.x;
      qm_t[c4*4 + 1][col] = q4.y*m4.y + w4.y;
      qm_t[c4*4 + 2][col] = q4.z*m4.z + w4.z;
      qm_t[c4*4 + 3][col] = q4.w*m4.w + w4.w;
    }
    __syncthreads();
    #pragma unroll 4
    for (int k4 = 0; k4 < 16; ++k4) {
      float ar[4][4], br[4][4];
      #pragma unroll
      for (int i = 0; i < 4; ++i) {
        float4 t4 = *(const float4*)&ctx_s[tr*4+i][k4*4];
        ar[i][0]=t4.x; ar[i][1]=t4.y; ar[i][2]=t4.z; ar[i][3]=t4.w;
      }
      const int colb = 4*(tc ^ k4);
      #pragma unroll
      for (int kk = 0; kk < 4; ++kk) {
        float4 t4 = *(const float4*)&qm_t[k4*4+kk][colb];
        br[kk][0]=t4.x; br[kk][1]=t4.y; br[kk][2]=t4.z; br[kk][3]=t4.w;
      }
      #pragma unroll
      for (int kk = 0; kk < 4; ++kk)
        #pragma unroll
        for (int i = 0; i < 4; ++i)
          #pragma unroll
          for (int jj = 0; jj < 4; ++jj)
            acc[i][jj] += ar[i][kk]*br[kk][jj];
    }
    __syncthreads();
  }
  // epilogue: S write + per-row max into LDS
  float4 qt4 = *(const float4*)(ws + QT_OFF + (size_t)b*JL + tc*4);
  float* Sp = ws + S_OFF + ((size_t)b*TT + t0)*JL;
  #pragma unroll
  for (int i = 0; i < 4; ++i) {
    float s0 = acc[i][0] + qt4.x;
    float s1 = acc[i][1] + qt4.y;
    float s2 = acc[i][2] + qt4.z;
    float s3 = acc[i][3] + qt4.w;
    *(float4*)(Sp + (size_t)(tr*4+i)*JL + tc*4) = make_float4(s0,s1,s2,s3);
    float rm = fmaxf(fmaxf(s0,s1), fmaxf(s2,s3));
    #pragma unroll
    for (int o = 1; o < 16; o <<= 1) rm = fmaxf(rm, __shfl_xor(rm, o));
    if (tc == 0) m_s[tr*4+i] = rm;
  }
  __syncthreads();
  // wave 0: tile max, weights, partial denominator
  if (tid < 64) {
    float mv = m_s[tid];
    float M = mv;
    #pragma unroll
    for (int o = 1; o < 64; o <<= 1) M = fmaxf(M, __shfl_xor(M, o));
    float wv = __expf(mv - M);
    w_s[tid] = wv;
    float den = wv;
    #pragma unroll
    for (int o = 1; o < 64; o <<= 1) den += __shfl_xor(den, o);
    if (tid == 0) {
      ws[PDEN_OFF + b*NT + bx] = den;
      ws[PMAX_OFF + b*NT + bx] = M;
    }
  }
  __syncthreads();
  // partial q2c: sum_t w_s[t] * ctx[t0+t, :]  (tile is L2-hot from staging)
  {
    const int hc = tid * 4;
    const float* ctxb = ctx + (size_t)t0*HH + hc;
    float4 a = {0,0,0,0};
    #pragma unroll 8
    for (int t = 0; t < 64; ++t) {
      float wv = w_s[t];
      float4 vv = *(const float4*)(ctxb + (size_t)t*HH);
      a.x += wv*vv.x; a.y += wv*vv.y; a.z += wv*vv.z; a.w += wv*vv.w;
    }
    *(float4*)(ws + PQ_OFF + ((size_t)(b*NT + bx))*HH + hc) = a;
  }
}

// ---- k2: combine partials with flash rescale -> q2c[b,h] ----
__global__ __launch_bounds__(256) void k2(float* __restrict__ ws) {
  int b = blockIdx.x, tid = threadIdx.x;
  float M = -1e30f;
  #pragma unroll
  for (int c = 0; c < NT; ++c) M = fmaxf(M, ws[PMAX_OFF + b*NT + c]);
  float den = 0.f;
  #pragma unroll
  for (int c = 0; c < NT; ++c)
    den += __expf(ws[PMAX_OFF + b*NT + c] - M) * ws[PDEN_OFF + b*NT + c];
  float inv = 1.f / den;
  float4 a = {0,0,0,0};
  for (int c = 0; c < NT; ++c) {
    float e = __expf(ws[PMAX_OFF + b*NT + c] - M);
    float4 v = *(const float4*)(ws + PQ_OFF + ((size_t)(b*NT + c))*HH + tid*4);
    a.x += e*v.x; a.y += e*v.y; a.z += e*v.z; a.w += e*v.w;
  }
  a.x *= inv; a.y *= inv; a.z *= inv; a.w *= inv;
  *(float4*)(ws + Q2C_OFF + (size_t)b*HH + tid*4) = a;
}

// ---- k4: softmax_j(S) -> c2q -> G assembly (round-3 proven version) ----
__global__ __launch_bounds__(256) void k4(const float* __restrict__ enc,
                                          const float* __restrict__ ws,
                                          float* __restrict__ out) {
  __shared__ float4 P4[16][16];
  const int b = blockIdx.y, t0 = blockIdx.x*16, tid = threadIdx.x;
  const int r = tid >> 4, sub = tid & 15;
  const float* Sp = ws + S_OFF + ((size_t)b*TT + t0)*JL;
  float4 v = *(const float4*)(Sp + (size_t)r*JL + sub*4);
  float mx = fmaxf(fmaxf(v.x,v.y), fmaxf(v.z,v.w));
  #pragma unroll
  for (int o = 1; o < 16; o <<= 1) mx = fmaxf(mx, __shfl_xor(mx, o));
  float e0 = expf(v.x-mx), e1 = expf(v.y-mx), e2 = expf(v.z-mx), e3 = expf(v.w-mx);
  float s = e0+e1+e2+e3;
  #pragma unroll
  for (int o = 1; o < 16; o <<= 1) s += __shfl_xor(s, o);
  float inv = 1.f/s;
  P4[r][sub] = make_float4(e0*inv, e1*inv, e2*inv, e3*inv);
  __syncthreads();
  const float* qry = enc + (size_t)b*LL*HH;
  const float* ctx = enc + ((size_t)b*LL + JL)*HH + (size_t)t0*HH;
  float4 acc[16];
  #pragma unroll
  for (int i = 0; i < 16; ++i) acc[i] = make_float4(0,0,0,0);
  for (int jc = 0; jc < 16; ++jc) {
    float4 q0 = *(const float4*)(qry + (size_t)(jc*4+0)*HH + tid*4);
    float4 q1 = *(const float4*)(qry + (size_t)(jc*4+1)*HH + tid*4);
    float4 q2v = *(const float4*)(qry + (size_t)(jc*4+2)*HH + tid*4);
    float4 q3 = *(const float4*)(qry + (size_t)(jc*4+3)*HH + tid*4);
    #pragma unroll
    for (int rr = 0; rr < 16; ++rr) {
      float4 p = P4[rr][jc];
      acc[rr].x += p.x*q0.x + p.y*q1.x + p.z*q2v.x + p.w*q3.x;
      acc[rr].y += p.x*q0.y + p.y*q1.y + p.z*q2v.y + p.w*q3.y;
      acc[rr].z += p.x*q0.z + p.y*q1.z + p.z*q2v.z + p.w*q3.z;
      acc[rr].w += p.x*q0.w + p.y*q1.w + p.z*q2v.w + p.w*q3.w;
    }
  }
  float4 qc = *(const float4*)(ws + Q2C_OFF + (size_t)b*HH + tid*4);
  float* G = out + (size_t)BB*JL*HH + ((size_t)b*TT + t0)*4096;
  #pragma unroll
  for (int rr = 0; rr < 16; ++rr) {
    float4 cv = *(const float4*)(ctx + (size_t)rr*HH + tid*4);
    float4 c2 = acc[rr];
    float* Gr = G + (size_t)rr*4096;
    *(float4*)(Gr + tid*4)        = cv;
    *(float4*)(Gr + 1024 + tid*4) = c2;
    *(float4*)(Gr + 2048 + tid*4) = make_float4(cv.x*c2.x, cv.y*c2.y, cv.z*c2.z, cv.w*c2.w);
    *(float4*)(Gr + 3072 + tid*4) = make_float4(cv.x*qc.x, cv.y*qc.y, cv.z*qc.z, cv.w*qc.w);
  }
}

extern "C" void kernel_launch(void* const* d_in, const int* in_sizes, int n_in,
                              void* d_out, int out_size, void* d_ws, size_t ws_size,
                              hipStream_t stream) {
  const float* enc = (const float*)d_in[0];
  const float* w   = (const float*)d_in[1];
  float* out = (float*)d_out;
  float* ws  = (float*)d_ws;
  k0<<<dim3(JL, BB), 256, 0, stream>>>(enc, w, out, ws);
  k1<<<dim3(NT, BB), 256, 0, stream>>>(enc, w, ws);
  k2<<<BB, 256, 0, stream>>>(ws);
  k4<<<dim3(TT/16, BB), 256, 0, stream>>>(enc, ws, out);
}

// Round 6
// 125.232 us; speedup vs baseline: 1.2998x; 1.1525x over previous
//
#include <hip/hip_runtime.h>
#include <math.h>

#define BB 8
#define LL 2048
#define HH 1024
#define JL 64
#define TT 1984          // LL - JL
#define NT 31            // k1 tiles per batch (TT/64)

// workspace layout (float offsets)
#define S_OFF    0
#define S_SZ     (BB*TT*JL)
#define QT_OFF   (S_OFF + S_SZ)
#define QT_SZ    (BB*JL)
#define PQ_OFF   (QT_OFF + QT_SZ)
#define PQ_SZ    (BB*NT*HH)
#define PDEN_OFF (PQ_OFF + PQ_SZ)
#define PMAX_OFF (PDEN_OFF + 256)
#define Q2C_OFF  (PMAX_OFF + 256)

typedef __attribute__((ext_vector_type(8))) short bf16x8;
typedef __attribute__((ext_vector_type(4))) float f32x4;

__device__ inline ushort f2bf(float x) {
  uint u = __float_as_uint(x);
  return (ushort)((u + 0x7FFFu + ((u >> 16) & 1u)) >> 16);
}

// ---- k0: copy query to out, compute q_term[b,j] = <query[b,j,:], w_q> ----
__global__ __launch_bounds__(256) void k0(const float* __restrict__ enc,
                                          const float* __restrict__ w,
                                          float* __restrict__ out,
                                          float* __restrict__ ws) {
  int j = blockIdx.x, b = blockIdx.y, tid = threadIdx.x;
  const float* qrow = enc + ((size_t)b*LL + j)*HH;
  float4 v = *(const float4*)(qrow + tid*4);
  *(float4*)(out + ((size_t)b*JL + j)*HH + tid*4) = v;
  float4 wq = *(const float4*)(w + HH + tid*4);
  float a = v.x*wq.x + v.y*wq.y + v.z*wq.z + v.w*wq.w;
  #pragma unroll
  for (int o = 32; o > 0; o >>= 1) a += __shfl_xor(a, o);
  __shared__ float red[4];
  if ((tid & 63) == 0) red[tid >> 6] = a;
  __syncthreads();
  if (tid == 0) ws[QT_OFF + b*JL + j] = red[0]+red[1]+red[2]+red[3];
}

// ---- k1: S GEMM via bf16 MFMA + flash partial-q2c epilogue ----
// S = sum_h ctx[t,h]*(w_m[h]*q[j,h] + w_c[h]) + q_term[j]
// 64x64 tile, 4 waves: wave w owns rows [w*16, w*16+16).
__global__ __launch_bounds__(256) void k1(const float* __restrict__ enc,
                                          const float* __restrict__ w,
                                          float* __restrict__ ws) {
  __shared__ ushort ctx_s[64][72];   // [t_local][k-chunk 64 bf16 + 8 pad], 144B stride
  __shared__ ushort qm_s[64][72];    // [j][k-chunk]
  __shared__ float m_s[64];
  __shared__ float w_s[64];
  const int b = blockIdx.y, bx = blockIdx.x;
  const int t0 = bx * 64;
  const int tid = threadIdx.x;
  const int lane = tid & 63, wv = tid >> 6;
  const int fr = lane & 15, fg = lane >> 4;   // frag row/col, k-group
  const float* ctx = enc + ((size_t)b*LL + JL)*HH;
  const float* qry = enc + (size_t)b*LL*HH;
  const float* wc = w;
  const float* wm = w + 2*HH;
  f32x4 acc[4];
  #pragma unroll
  for (int n = 0; n < 4; ++n) acc[n] = (f32x4){0.f,0.f,0.f,0.f};
  const int sr = tid >> 2;          // staging row 0..63
  const int sc = (tid & 3) * 16;    // staging bf16 col base
  for (int h0 = 0; h0 < HH; h0 += 64) {
    #pragma unroll
    for (int q = 0; q < 4; ++q) {
      const int hc = h0 + sc + q*4;
      float4 cv = *(const float4*)(ctx + (size_t)(t0 + sr)*HH + hc);
      float4 qv = *(const float4*)(qry + (size_t)sr*HH + hc);
      float4 mv = *(const float4*)(wm + hc);
      float4 wvv = *(const float4*)(wc + hc);
      ushort4 cb = make_ushort4(f2bf(cv.x), f2bf(cv.y), f2bf(cv.z), f2bf(cv.w));
      ushort4 qb = make_ushort4(f2bf(qv.x*mv.x + wvv.x), f2bf(qv.y*mv.y + wvv.y),
                                f2bf(qv.z*mv.z + wvv.z), f2bf(qv.w*mv.w + wvv.w));
      *(ushort4*)&ctx_s[sr][sc + q*4] = cb;
      *(ushort4*)&qm_s[sr][sc + q*4] = qb;
    }
    __syncthreads();
    #pragma unroll
    for (int kk = 0; kk < 2; ++kk) {
      bf16x8 a = *(const bf16x8*)&ctx_s[wv*16 + fr][kk*32 + fg*8];
      #pragma unroll
      for (int n = 0; n < 4; ++n) {
        bf16x8 bb = *(const bf16x8*)&qm_s[n*16 + fr][kk*32 + fg*8];
        acc[n] = __builtin_amdgcn_mfma_f32_16x16x32_bf16(a, bb, acc[n], 0, 0, 0);
      }
    }
    __syncthreads();
  }
  // S = acc + q_term; write S, per-row max (row = wv*16 + fg*4 + r, col = n*16 + fr)
  float qt[4];
  #pragma unroll
  for (int n = 0; n < 4; ++n) qt[n] = ws[QT_OFF + (size_t)b*JL + n*16 + fr];
  float* Sp = ws + S_OFF + ((size_t)b*TT + t0)*JL;
  #pragma unroll
  for (int r = 0; r < 4; ++r) {
    const int row = wv*16 + fg*4 + r;
    float s0 = acc[0][r] + qt[0];
    float s1 = acc[1][r] + qt[1];
    float s2 = acc[2][r] + qt[2];
    float s3 = acc[3][r] + qt[3];
    Sp[(size_t)row*JL +      fr] = s0;
    Sp[(size_t)row*JL + 16 + fr] = s1;
    Sp[(size_t)row*JL + 32 + fr] = s2;
    Sp[(size_t)row*JL + 48 + fr] = s3;
    float rm = fmaxf(fmaxf(s0,s1), fmaxf(s2,s3));
    #pragma unroll
    for (int o = 1; o < 16; o <<= 1) rm = fmaxf(rm, __shfl_xor(rm, o));
    if (fr == 0) m_s[row] = rm;
  }
  __syncthreads();
  // wave 0: tile max, weights, partial denominator
  if (tid < 64) {
    float mv2 = m_s[tid];
    float M = mv2;
    #pragma unroll
    for (int o = 1; o < 64; o <<= 1) M = fmaxf(M, __shfl_xor(M, o));
    float wv2 = __expf(mv2 - M);
    w_s[tid] = wv2;
    float den = wv2;
    #pragma unroll
    for (int o = 1; o < 64; o <<= 1) den += __shfl_xor(den, o);
    if (tid == 0) {
      ws[PDEN_OFF + b*NT + bx] = den;
      ws[PMAX_OFF + b*NT + bx] = M;
    }
  }
  __syncthreads();
  // partial q2c: sum_t w_s[t] * ctx[t0+t, :]  (tile L2/L3-hot from staging)
  {
    const int hc = tid * 4;
    const float* ctxb = ctx + (size_t)t0*HH + hc;
    float4 a0 = {0,0,0,0}, a1 = {0,0,0,0};
    #pragma unroll 8
    for (int t = 0; t < 64; t += 2) {
      float w0 = w_s[t], w1 = w_s[t+1];
      float4 v0 = *(const float4*)(ctxb + (size_t)t*HH);
      float4 v1 = *(const float4*)(ctxb + (size_t)(t+1)*HH);
      a0.x += w0*v0.x; a0.y += w0*v0.y; a0.z += w0*v0.z; a0.w += w0*v0.w;
      a1.x += w1*v1.x; a1.y += w1*v1.y; a1.z += w1*v1.z; a1.w += w1*v1.w;
    }
    a0.x += a1.x; a0.y += a1.y; a0.z += a1.z; a0.w += a1.w;
    *(float4*)(ws + PQ_OFF + ((size_t)(b*NT + bx))*HH + hc) = a0;
  }
}

// ---- k2: combine partials with flash rescale -> q2c[b,h] ----
__global__ __launch_bounds__(256) void k2(float* __restrict__ ws) {
  int b = blockIdx.x, tid = threadIdx.x;
  float M = -1e30f;
  #pragma unroll
  for (int c = 0; c < NT; ++c) M = fmaxf(M, ws[PMAX_OFF + b*NT + c]);
  float den = 0.f;
  #pragma unroll
  for (int c = 0; c < NT; ++c)
    den += __expf(ws[PMAX_OFF + b*NT + c] - M) * ws[PDEN_OFF + b*NT + c];
  float inv = 1.f / den;
  float4 a = {0,0,0,0};
  for (int c = 0; c < NT; ++c) {
    float e = __expf(ws[PMAX_OFF + b*NT + c] - M);
    float4 v = *(const float4*)(ws + PQ_OFF + ((size_t)(b*NT + c))*HH + tid*4);
    a.x += e*v.x; a.y += e*v.y; a.z += e*v.z; a.w += e*v.w;
  }
  a.x *= inv; a.y *= inv; a.z *= inv; a.w *= inv;
  *(float4*)(ws + Q2C_OFF + (size_t)b*HH + tid*4) = a;
}

// ---- k4: softmax_j(S) -> c2q -> G assembly ----
__global__ __launch_bounds__(256) void k4(const float* __restrict__ enc,
                                          const float* __restrict__ ws,
                                          float* __restrict__ out) {
  __shared__ float4 P4[16][16];
  const int b = blockIdx.y, t0 = blockIdx.x*16, tid = threadIdx.x;
  const int r = tid >> 4, sub = tid & 15;
  const float* Sp = ws + S_OFF + ((size_t)b*TT + t0)*JL;
  float4 v = *(const float4*)(Sp + (size_t)r*JL + sub*4);
  float mx = fmaxf(fmaxf(v.x,v.y), fmaxf(v.z,v.w));
  #pragma unroll
  for (int o = 1; o < 16; o <<= 1) mx = fmaxf(mx, __shfl_xor(mx, o));
  float e0 = expf(v.x-mx), e1 = expf(v.y-mx), e2 = expf(v.z-mx), e3 = expf(v.w-mx);
  float s = e0+e1+e2+e3;
  #pragma unroll
  for (int o = 1; o < 16; o <<= 1) s += __shfl_xor(s, o);
  float inv = 1.f/s;
  P4[r][sub] = make_float4(e0*inv, e1*inv, e2*inv, e3*inv);
  __syncthreads();
  const float* qry = enc + (size_t)b*LL*HH;
  const float* ctx = enc + ((size_t)b*LL + JL)*HH + (size_t)t0*HH;
  float4 acc[16];
  #pragma unroll
  for (int i = 0; i < 16; ++i) acc[i] = make_float4(0,0,0,0);
  for (int jc = 0; jc < 16; ++jc) {
    float4 q0 = *(const float4*)(qry + (size_t)(jc*4+0)*HH + tid*4);
    float4 q1 = *(const float4*)(qry + (size_t)(jc*4+1)*HH + tid*4);
    float4 q2v = *(const float4*)(qry + (size_t)(jc*4+2)*HH + tid*4);
    float4 q3 = *(const float4*)(qry + (size_t)(jc*4+3)*HH + tid*4);
    #pragma unroll
    for (int rr = 0; rr < 16; ++rr) {
      float4 p = P4[rr][jc];
      acc[rr].x += p.x*q0.x + p.y*q1.x + p.z*q2v.x + p.w*q3.x;
      acc[rr].y += p.x*q0.y + p.y*q1.y + p.z*q2v.y + p.w*q3.y;
      acc[rr].z += p.x*q0.z + p.y*q1.z + p.z*q2v.z + p.w*q3.z;
      acc[rr].w += p.x*q0.w + p.y*q1.w + p.z*q2v.w + p.w*q3.w;
    }
  }
  float4 qc = *(const float4*)(ws + Q2C_OFF + (size_t)b*HH + tid*4);
  float* G = out + (size_t)BB*JL*HH + ((size_t)b*TT + t0)*4096;
  #pragma unroll
  for (int rr = 0; rr < 16; ++rr) {
    float4 cv = *(const float4*)(ctx + (size_t)rr*HH + tid*4);
    float4 c2 = acc[rr];
    float* Gr = G + (size_t)rr*4096;
    *(float4*)(Gr + tid*4)        = cv;
    *(float4*)(Gr + 1024 + tid*4) = c2;
    *(float4*)(Gr + 2048 + tid*4) = make_float4(cv.x*c2.x, cv.y*c2.y, cv.z*c2.z, cv.w*c2.w);
    *(float4*)(Gr + 3072 + tid*4) = make_float4(cv.x*qc.x, cv.y*qc.y, cv.z*qc.z, cv.w*qc.w);
  }
}

extern "C" void kernel_launch(void* const* d_in, const int* in_sizes, int n_in,
                              void* d_out, int out_size, void* d_ws, size_t ws_size,
                              hipStream_t stream) {
  const float* enc = (const float*)d_in[0];
  const float* w   = (const float*)d_in[1];
  float* out = (float*)d_out;
  float* ws  = (float*)d_ws;
  k0<<<dim3(JL, BB), 256, 0, stream>>>(enc, w, out, ws);
  k1<<<dim3(NT, BB), 256, 0, stream>>>(enc, w, ws);
  k2<<<BB, 256, 0, stream>>>(ws);
  k4<<<dim3(TT/16, BB), 256, 0, stream>>>(enc, ws, out);
}